// Round 1
// baseline (209.034 us; speedup 1.0000x reference)
//
#include <hip/hip_runtime.h>

#define DIM 512
#define HIDDEN 1024
#define H2 2048        // 2*HIDDEN
#define NEXP 32
#define TOPK 4
#define TOKENS 64
#define NPAIR (TOKENS*TOPK)   // 256

// ---------------- router: logits + top4 + softmax ----------------
__global__ void router_kernel(const float* __restrict__ x, const float* __restrict__ Wg,
                              const float* __restrict__ bg, int* __restrict__ idxw,
                              float* __restrict__ eww) {
    int b = blockIdx.x;
    int e = threadIdx.x;          // 64 threads, first 32 compute logits
    __shared__ float g[NEXP];
    if (e < NEXP) {
        const float* xr = x + b * DIM;
        const float* wr = Wg + e * DIM;
        float acc = 0.f;
        for (int d = 0; d < DIM; d += 4) {
            float4 xv = *(const float4*)(xr + d);
            float4 wv = *(const float4*)(wr + d);
            acc += xv.x*wv.x + xv.y*wv.y + xv.z*wv.z + xv.w*wv.w;
        }
        g[e] = acc + bg[e];
    }
    __syncthreads();
    if (threadIdx.x == 0) {
        int sel[TOPK]; float val[TOPK];
        bool used[NEXP];
        for (int i = 0; i < NEXP; ++i) used[i] = false;
        for (int k = 0; k < TOPK; ++k) {
            float best = -1e30f; int bi = 0;
            for (int ee = 0; ee < NEXP; ++ee) {
                if (!used[ee] && g[ee] > best) { best = g[ee]; bi = ee; }
            }
            used[bi] = true; sel[k] = bi; val[k] = best;
        }
        float m = val[0];        // val[0] is the max
        float p[TOPK]; float s = 0.f;
        for (int k = 0; k < TOPK; ++k) { p[k] = __expf(val[k] - m); s += p[k]; }
        float inv = 1.f / s;
        for (int k = 0; k < TOPK; ++k) {
            idxw[b*TOPK + k] = sel[k];
            eww[b*TOPK + k]  = p[k] * inv;
        }
    }
}

// ---------------- deterministic per-expert list build ----------------
__global__ void build_lists(const int* __restrict__ idxw, int* __restrict__ counts,
                            int* __restrict__ lists) {
    int e = threadIdx.x;
    if (e >= NEXP) return;
    int cnt = 0;
    for (int p = 0; p < NPAIR; ++p) {
        if (idxw[p] == e) lists[e*TOKENS + cnt++] = p;
    }
    counts[e] = cnt;
}

// ---------------- expert up-proj + swiglu ----------------
#define TC 16
__global__ void expert_up(const float* __restrict__ x, const float* __restrict__ w1,
                          const float* __restrict__ b1, const int* __restrict__ counts,
                          const int* __restrict__ lists, float* __restrict__ act) {
    int e = blockIdx.x;
    int n = counts[e];
    if (n == 0) return;
    int c = blockIdx.y * 128 + threadIdx.x;   // activation channel 0..1023
    const float4* w0p = (const float4*)(w1 + ((size_t)e*H2 + 2*c    ) * DIM);
    const float4* w1p = (const float4*)(w1 + ((size_t)e*H2 + 2*c + 1) * DIM);
    float be = b1[e*H2 + 2*c];
    float bo = b1[e*H2 + 2*c + 1];
    __shared__ float xs[TC][DIM];
    for (int t0 = 0; t0 < n; t0 += TC) {
        int tc = min(TC, n - t0);
        __syncthreads();   // protect xs from previous iteration's readers
        for (int i = threadIdx.x; i < TC*(DIM/4); i += 128) {
            int j = i / (DIM/4); int dd = i % (DIM/4);
            float4 v = make_float4(0.f, 0.f, 0.f, 0.f);
            if (j < tc) {
                int p = lists[e*TOKENS + t0 + j];
                int tok = p >> 2;
                v = *(const float4*)(x + (size_t)tok*DIM + dd*4);
            }
            *(float4*)&xs[j][dd*4] = v;
        }
        __syncthreads();
        float a0[TC], a1[TC];
        #pragma unroll
        for (int j = 0; j < TC; ++j) { a0[j] = 0.f; a1[j] = 0.f; }
        for (int d4 = 0; d4 < DIM/4; ++d4) {
            float4 w0 = w0p[d4];
            float4 w1v = w1p[d4];
            #pragma unroll
            for (int j = 0; j < TC; ++j) {
                float4 xv = *(const float4*)&xs[j][d4*4];
                a0[j] += w0.x*xv.x + w0.y*xv.y + w0.z*xv.z + w0.w*xv.w;
                a1[j] += w1v.x*xv.x + w1v.y*xv.y + w1v.z*xv.z + w1v.w*xv.w;
            }
        }
        for (int j = 0; j < tc; ++j) {
            int p = lists[e*TOKENS + t0 + j];
            float h0 = a0[j] + be;
            float h1 = a1[j] + bo;
            float gv = fminf(h0, 7.f);
            float lv = fminf(fmaxf(h1, -7.f), 7.f);
            float sg = 1.f / (1.f + __expf(-1.702f * gv));
            act[(size_t)p*HIDDEN + c] = gv * sg * (lv + 1.f);
        }
    }
}

// ---------------- expert down-proj ----------------
#define TCD 8
__global__ void expert_down(const float* __restrict__ act, const float* __restrict__ w2,
                            const float* __restrict__ b2, const int* __restrict__ counts,
                            const int* __restrict__ lists, float* __restrict__ h2) {
    int e = blockIdx.x;
    int n = counts[e];
    if (n == 0) return;
    int c = blockIdx.y * 64 + threadIdx.x;   // output dim 0..511
    const float4* wp = (const float4*)(w2 + ((size_t)e*DIM + c) * HIDDEN);
    float bb = b2[e*DIM + c];
    __shared__ float hs[TCD][HIDDEN];
    for (int t0 = 0; t0 < n; t0 += TCD) {
        int tc = min(TCD, n - t0);
        __syncthreads();
        for (int i = threadIdx.x; i < TCD*(HIDDEN/4); i += 64) {
            int j = i / (HIDDEN/4); int dd = i % (HIDDEN/4);
            float4 v = make_float4(0.f, 0.f, 0.f, 0.f);
            if (j < tc) {
                int p = lists[e*TOKENS + t0 + j];
                v = *(const float4*)(act + (size_t)p*HIDDEN + dd*4);
            }
            *(float4*)&hs[j][dd*4] = v;
        }
        __syncthreads();
        float a[TCD];
        #pragma unroll
        for (int j = 0; j < TCD; ++j) a[j] = 0.f;
        for (int d4 = 0; d4 < HIDDEN/4; ++d4) {
            float4 w = wp[d4];
            #pragma unroll
            for (int j = 0; j < TCD; ++j) {
                float4 hv = *(const float4*)&hs[j][d4*4];
                a[j] += w.x*hv.x + w.y*hv.y + w.z*hv.z + w.w*hv.w;
            }
        }
        for (int j = 0; j < tc; ++j) {
            int p = lists[e*TOKENS + t0 + j];
            h2[(size_t)p*DIM + c] = a[j] + bb;
        }
    }
}

// ---------------- weighted combine ----------------
__global__ void combine_kernel(const float* __restrict__ h2, const float* __restrict__ eww,
                               float* __restrict__ out) {
    int i = blockIdx.x * 256 + threadIdx.x;   // 0..32767
    int b = i / DIM;
    int c = i % DIM;
    float s = 0.f;
    #pragma unroll
    for (int k = 0; k < TOPK; ++k) {
        s += eww[b*TOPK + k] * h2[(size_t)(b*TOPK + k)*DIM + c];
    }
    out[i] = s;
}

extern "C" void kernel_launch(void* const* d_in, const int* in_sizes, int n_in,
                              void* d_out, int out_size, void* d_ws, size_t ws_size,
                              hipStream_t stream) {
    const float* x  = (const float*)d_in[0];
    const float* Wg = (const float*)d_in[1];
    const float* bg = (const float*)d_in[2];
    const float* w1 = (const float*)d_in[3];
    const float* b1 = (const float*)d_in[4];
    const float* w2 = (const float*)d_in[5];
    const float* b2 = (const float*)d_in[6];
    float* out = (float*)d_out;

    char* ws = (char*)d_ws;
    int*   idxw   = (int*)(ws);                 // 256 ints
    float* eww    = (float*)(ws + 1024);        // 256 floats
    int*   counts = (int*)(ws + 2048);          // 32 ints
    int*   lists  = (int*)(ws + 4096);          // 32*64 ints
    float* act    = (float*)(ws + 16384);                        // 256*1024 f32 = 1 MB
    float* h2     = (float*)(ws + 16384 + (size_t)NPAIR*HIDDEN*4); // 256*512 f32 = 512 KB

    router_kernel<<<TOKENS, 64, 0, stream>>>(x, Wg, bg, idxw, eww);
    build_lists<<<1, 32, 0, stream>>>(idxw, counts, lists);
    expert_up<<<dim3(NEXP, 8), 128, 0, stream>>>(x, w1, b1, counts, lists, act);
    expert_down<<<dim3(NEXP, 8), 64, 0, stream>>>(act, w2, b2, counts, lists, h2);
    combine_kernel<<<TOKENS*DIM/256, 256, 0, stream>>>(h2, eww, out);
}

// Round 2
// 176.587 us; speedup vs baseline: 1.1837x; 1.1837x over previous
//
#include <hip/hip_runtime.h>

#define DIM 512
#define HIDDEN 1024
#define H2 2048        // 2*HIDDEN
#define NEXP 32
#define TOPK 4
#define TOKENS 64
#define NPAIR (TOKENS*TOPK)   // 256

// ---------------- router: logits + top4 + softmax ----------------
__global__ void router_kernel(const float* __restrict__ x, const float* __restrict__ Wg,
                              const float* __restrict__ bg, int* __restrict__ idxw,
                              float* __restrict__ eww) {
    int b = blockIdx.x;
    int e = threadIdx.x;          // 64 threads, first 32 compute logits
    __shared__ float g[NEXP];
    if (e < NEXP) {
        const float* xr = x + b * DIM;
        const float* wr = Wg + e * DIM;
        float acc = 0.f;
        for (int d = 0; d < DIM; d += 4) {
            float4 xv = *(const float4*)(xr + d);
            float4 wv = *(const float4*)(wr + d);
            acc += xv.x*wv.x + xv.y*wv.y + xv.z*wv.z + xv.w*wv.w;
        }
        g[e] = acc + bg[e];
    }
    __syncthreads();
    if (threadIdx.x == 0) {
        int sel[TOPK]; float val[TOPK];
        bool used[NEXP];
        for (int i = 0; i < NEXP; ++i) used[i] = false;
        for (int k = 0; k < TOPK; ++k) {
            float best = -1e30f; int bi = 0;
            for (int ee = 0; ee < NEXP; ++ee) {
                if (!used[ee] && g[ee] > best) { best = g[ee]; bi = ee; }
            }
            used[bi] = true; sel[k] = bi; val[k] = best;
        }
        float m = val[0];        // val[0] is the max
        float p[TOPK]; float s = 0.f;
        for (int k = 0; k < TOPK; ++k) { p[k] = __expf(val[k] - m); s += p[k]; }
        float inv = 1.f / s;
        for (int k = 0; k < TOPK; ++k) {
            idxw[b*TOPK + k] = sel[k];
            eww[b*TOPK + k]  = p[k] * inv;
        }
    }
}

// ---------------- deterministic per-expert list build ----------------
__global__ void build_lists(const int* __restrict__ idxw, int* __restrict__ counts,
                            int* __restrict__ lists) {
    int e = threadIdx.x;
    if (e >= NEXP) return;
    int cnt = 0;
    for (int p = 0; p < NPAIR; ++p) {
        if (idxw[p] == e) lists[e*TOKENS + cnt++] = p;
    }
    counts[e] = cnt;
}

// ---------------- expert up-proj + swiglu (8-way split-K) ----------------
// block: 256 thr = 32 channels x 8 splits. grid: (NEXP, HIDDEN/32 = 32)
#define TC 8
__global__ __launch_bounds__(256) void expert_up(
        const float* __restrict__ x, const float* __restrict__ w1,
        const float* __restrict__ b1, const int* __restrict__ counts,
        const int* __restrict__ lists, float* __restrict__ act) {
    int e = blockIdx.x;
    int n = counts[e];
    if (n == 0) return;
    int tid = threadIdx.x;
    int c_local = tid >> 3;
    int s = tid & 7;
    int c = blockIdx.y * 32 + c_local;    // activation channel 0..1023
    const float4* w0p = (const float4*)(w1 + ((size_t)e*H2 + 2*c    ) * DIM);
    const float4* w1p = (const float4*)(w1 + ((size_t)e*H2 + 2*c + 1) * DIM);
    __shared__ float xs[TC][DIM];         // 16 KB
    for (int t0 = 0; t0 < n; t0 += TC) {
        int tc = min(TC, n - t0);
        __syncthreads();   // protect xs from previous iteration's readers
        for (int i = tid; i < TC*(DIM/4); i += 256) {
            int j = i >> 7; int dd = i & 127;          // DIM/4 = 128
            float4 v = make_float4(0.f, 0.f, 0.f, 0.f);
            if (j < tc) {
                int p = lists[e*TOKENS + t0 + j];
                int tok = p >> 2;
                v = *(const float4*)(x + (size_t)tok*DIM + dd*4);
            }
            *(float4*)&xs[j][dd*4] = v;
        }
        __syncthreads();
        float a0[TC], a1[TC];
        #pragma unroll
        for (int j = 0; j < TC; ++j) { a0[j] = 0.f; a1[j] = 0.f; }
        #pragma unroll
        for (int i = 0; i < 16; ++i) {                 // 128 f4 / 8 splits
            int d4 = s + 8*i;
            float4 w0 = w0p[d4];
            float4 wv = w1p[d4];
            #pragma unroll
            for (int j = 0; j < TC; ++j) {
                float4 xv = *(const float4*)&xs[j][d4*4];
                a0[j] += w0.x*xv.x + w0.y*xv.y + w0.z*xv.z + w0.w*xv.w;
                a1[j] += wv.x*xv.x + wv.y*xv.y + wv.z*xv.z + wv.w*xv.w;
            }
        }
        // reduce across the 8 aligned lanes of the split group
        #pragma unroll
        for (int j = 0; j < TC; ++j) {
            #pragma unroll
            for (int m = 1; m < 8; m <<= 1) {
                a0[j] += __shfl_xor(a0[j], m);
                a1[j] += __shfl_xor(a1[j], m);
            }
        }
        if (s == 0) {
            float be = b1[e*H2 + 2*c];
            float bo = b1[e*H2 + 2*c + 1];
            for (int j = 0; j < tc; ++j) {
                int p = lists[e*TOKENS + t0 + j];
                float h0 = a0[j] + be;
                float h1 = a1[j] + bo;
                float gv = fminf(h0, 7.f);
                float lv = fminf(fmaxf(h1, -7.f), 7.f);
                float sg = 1.f / (1.f + __expf(-1.702f * gv));
                act[(size_t)p*HIDDEN + c] = gv * sg * (lv + 1.f);
            }
        }
    }
}

// ---------------- expert down-proj (8-way split-K) ----------------
// block: 256 thr = 32 channels x 8 splits. grid: (NEXP, DIM/32 = 16)
#define TCD 8
__global__ __launch_bounds__(256) void expert_down(
        const float* __restrict__ act, const float* __restrict__ w2,
        const float* __restrict__ b2, const int* __restrict__ counts,
        const int* __restrict__ lists, float* __restrict__ h2) {
    int e = blockIdx.x;
    int n = counts[e];
    if (n == 0) return;
    int tid = threadIdx.x;
    int c_local = tid >> 3;
    int s = tid & 7;
    int c = blockIdx.y * 32 + c_local;    // output dim 0..511
    const float4* wp = (const float4*)(w2 + ((size_t)e*DIM + c) * HIDDEN);
    __shared__ float hs[TCD][HIDDEN];     // 32 KB
    for (int t0 = 0; t0 < n; t0 += TCD) {
        int tc = min(TCD, n - t0);
        __syncthreads();
        for (int i = tid; i < TCD*(HIDDEN/4); i += 256) {
            int j = i >> 8; int dd = i & 255;          // HIDDEN/4 = 256
            float4 v = make_float4(0.f, 0.f, 0.f, 0.f);
            if (j < tc) {
                int p = lists[e*TOKENS + t0 + j];
                v = *(const float4*)(act + (size_t)p*HIDDEN + dd*4);
            }
            *(float4*)&hs[j][dd*4] = v;
        }
        __syncthreads();
        float a[TCD];
        #pragma unroll
        for (int j = 0; j < TCD; ++j) a[j] = 0.f;
        #pragma unroll
        for (int i = 0; i < 32; ++i) {                 // 256 f4 / 8 splits
            int d4 = s + 8*i;
            float4 w = wp[d4];
            #pragma unroll
            for (int j = 0; j < TCD; ++j) {
                float4 hv = *(const float4*)&hs[j][d4*4];
                a[j] += w.x*hv.x + w.y*hv.y + w.z*hv.z + w.w*hv.w;
            }
        }
        #pragma unroll
        for (int j = 0; j < TCD; ++j) {
            #pragma unroll
            for (int m = 1; m < 8; m <<= 1) {
                a[j] += __shfl_xor(a[j], m);
            }
        }
        if (s == 0) {
            float bb = b2[e*DIM + c];
            for (int j = 0; j < tc; ++j) {
                int p = lists[e*TOKENS + t0 + j];
                h2[(size_t)p*DIM + c] = a[j] + bb;
            }
        }
    }
}

// ---------------- weighted combine ----------------
__global__ void combine_kernel(const float* __restrict__ h2, const float* __restrict__ eww,
                               float* __restrict__ out) {
    int i = blockIdx.x * 256 + threadIdx.x;   // 0..32767
    int b = i / DIM;
    int c = i % DIM;
    float s = 0.f;
    #pragma unroll
    for (int k = 0; k < TOPK; ++k) {
        s += eww[b*TOPK + k] * h2[(size_t)(b*TOPK + k)*DIM + c];
    }
    out[i] = s;
}

extern "C" void kernel_launch(void* const* d_in, const int* in_sizes, int n_in,
                              void* d_out, int out_size, void* d_ws, size_t ws_size,
                              hipStream_t stream) {
    const float* x  = (const float*)d_in[0];
    const float* Wg = (const float*)d_in[1];
    const float* bg = (const float*)d_in[2];
    const float* w1 = (const float*)d_in[3];
    const float* b1 = (const float*)d_in[4];
    const float* w2 = (const float*)d_in[5];
    const float* b2 = (const float*)d_in[6];
    float* out = (float*)d_out;

    char* ws = (char*)d_ws;
    int*   idxw   = (int*)(ws);                 // 256 ints
    float* eww    = (float*)(ws + 1024);        // 256 floats
    int*   counts = (int*)(ws + 2048);          // 32 ints
    int*   lists  = (int*)(ws + 4096);          // 32*64 ints
    float* act    = (float*)(ws + 16384);                          // 256*1024 f32 = 1 MB
    float* h2     = (float*)(ws + 16384 + (size_t)NPAIR*HIDDEN*4); // 256*512 f32 = 512 KB

    router_kernel<<<TOKENS, 64, 0, stream>>>(x, Wg, bg, idxw, eww);
    build_lists<<<1, 32, 0, stream>>>(idxw, counts, lists);
    expert_up<<<dim3(NEXP, HIDDEN/32), 256, 0, stream>>>(x, w1, b1, counts, lists, act);
    expert_down<<<dim3(NEXP, DIM/32), 256, 0, stream>>>(act, w2, b2, counts, lists, h2);
    combine_kernel<<<TOKENS*DIM/256, 256, 0, stream>>>(h2, eww, out);
}

// Round 3
// 111.054 us; speedup vs baseline: 1.8823x; 1.5901x over previous
//
#include <hip/hip_runtime.h>

#define DIM 512
#define HIDDEN 1024
#define H2 2048        // 2*HIDDEN
#define NEXP 32
#define TOPK 4
#define TOKENS 64
#define NPAIR (TOKENS*TOPK)   // 256

// ---------------- router: logits + top4 + softmax ----------------
__global__ void router_kernel(const float* __restrict__ x, const float* __restrict__ Wg,
                              const float* __restrict__ bg, int* __restrict__ idxw,
                              float* __restrict__ eww) {
    int b = blockIdx.x;
    int e = threadIdx.x;          // 64 threads, first 32 compute logits
    __shared__ float g[NEXP];
    if (e < NEXP) {
        const float* xr = x + b * DIM;
        const float* wr = Wg + e * DIM;
        float acc = 0.f;
        for (int d = 0; d < DIM; d += 4) {
            float4 xv = *(const float4*)(xr + d);
            float4 wv = *(const float4*)(wr + d);
            acc += xv.x*wv.x + xv.y*wv.y + xv.z*wv.z + xv.w*wv.w;
        }
        g[e] = acc + bg[e];
    }
    __syncthreads();
    if (threadIdx.x == 0) {
        int sel[TOPK]; float val[TOPK];
        bool used[NEXP];
        for (int i = 0; i < NEXP; ++i) used[i] = false;
        for (int k = 0; k < TOPK; ++k) {
            float best = -1e30f; int bi = 0;
            for (int ee = 0; ee < NEXP; ++ee) {
                if (!used[ee] && g[ee] > best) { best = g[ee]; bi = ee; }
            }
            used[bi] = true; sel[k] = bi; val[k] = best;
        }
        float m = val[0];        // val[0] is the max
        float p[TOPK]; float s = 0.f;
        for (int k = 0; k < TOPK; ++k) { p[k] = __expf(val[k] - m); s += p[k]; }
        float inv = 1.f / s;
        for (int k = 0; k < TOPK; ++k) {
            idxw[b*TOPK + k] = sel[k];
            eww[b*TOPK + k]  = p[k] * inv;
        }
    }
}

// ---------------- deterministic per-expert list build ----------------
__global__ void build_lists(const int* __restrict__ idxw, int* __restrict__ counts,
                            int* __restrict__ lists) {
    int e = threadIdx.x;
    if (e >= NEXP) return;
    int cnt = 0;
    for (int p = 0; p < NPAIR; ++p) {
        if (idxw[p] == e) lists[e*TOKENS + cnt++] = p;
    }
    counts[e] = cnt;
}

// ---------------- expert up-proj + swiglu (16-way split-K) ----------------
// block: 256 thr = 16 channel-pairs x 16 splits. grid: (NEXP, HIDDEN/16 = 64)
#define TC 8
__global__ __launch_bounds__(256, 4) void expert_up(
        const float* __restrict__ x, const float* __restrict__ w1,
        const float* __restrict__ b1, const int* __restrict__ counts,
        const int* __restrict__ lists, float* __restrict__ act) {
    int e = blockIdx.x;
    int n = counts[e];
    if (n == 0) return;
    int tid = threadIdx.x;
    int cl = tid >> 4;                    // 0..15
    int s  = tid & 15;                    // 0..15
    int c = blockIdx.y * 16 + cl;         // activation channel 0..1023
    // rows 2c and 2c+1 are contiguous in w1
    const float4* w0p = (const float4*)(w1 + ((size_t)e*H2 + 2*c) * DIM);
    const float4* w1p = w0p + DIM/4;
    __shared__ float xs[TC][DIM];         // 16 KB
    for (int t0 = 0; t0 < n; t0 += TC) {
        int tc = min(TC, n - t0);
        __syncthreads();   // protect xs from previous iteration's readers
        for (int i = tid; i < TC*(DIM/4); i += 256) {
            int j = i >> 7; int dd = i & 127;          // DIM/4 = 128
            float4 v = make_float4(0.f, 0.f, 0.f, 0.f);
            if (j < tc) {
                int p = lists[e*TOKENS + t0 + j];
                int tok = p >> 2;
                v = *(const float4*)(x + (size_t)tok*DIM + dd*4);
            }
            *(float4*)&xs[j][dd*4] = v;
        }
        __syncthreads();
        float a0[TC], a1[TC];
        #pragma unroll
        for (int j = 0; j < TC; ++j) { a0[j] = 0.f; a1[j] = 0.f; }
        #pragma unroll 4
        for (int i = 0; i < 8; ++i) {                  // 128 f4 / 16 splits
            int d4 = s + 16*i;
            float4 w0 = w0p[d4];
            float4 wv = w1p[d4];
            #pragma unroll
            for (int j = 0; j < TC; ++j) {
                float4 xv = *(const float4*)&xs[j][d4*4];
                a0[j] += w0.x*xv.x + w0.y*xv.y + w0.z*xv.z + w0.w*xv.w;
                a1[j] += wv.x*xv.x + wv.y*xv.y + wv.z*xv.z + wv.w*xv.w;
            }
        }
        // reduce across the 16 aligned lanes of the split group
        #pragma unroll
        for (int j = 0; j < TC; ++j) {
            #pragma unroll
            for (int m = 1; m < 16; m <<= 1) {
                a0[j] += __shfl_xor(a0[j], m);
                a1[j] += __shfl_xor(a1[j], m);
            }
        }
        if (s == 0) {
            float be = b1[e*H2 + 2*c];
            float bo = b1[e*H2 + 2*c + 1];
            for (int j = 0; j < tc; ++j) {
                int p = lists[e*TOKENS + t0 + j];
                float h0 = a0[j] + be;
                float h1 = a1[j] + bo;
                float gv = fminf(h0, 7.f);
                float lv = fminf(fmaxf(h1, -7.f), 7.f);
                float sg = 1.f / (1.f + __expf(-1.702f * gv));
                act[(size_t)p*HIDDEN + c] = gv * sg * (lv + 1.f);
            }
        }
    }
}

// ---------------- expert down-proj (16-way split-K) ----------------
// block: 256 thr = 16 channels x 16 splits. grid: (NEXP, DIM/16 = 32)
#define TCD 8
__global__ __launch_bounds__(256, 4) void expert_down(
        const float* __restrict__ act, const float* __restrict__ w2,
        const float* __restrict__ b2, const int* __restrict__ counts,
        const int* __restrict__ lists, float* __restrict__ h2) {
    int e = blockIdx.x;
    int n = counts[e];
    if (n == 0) return;
    int tid = threadIdx.x;
    int cl = tid >> 4;
    int s  = tid & 15;
    int c = blockIdx.y * 16 + cl;         // output dim 0..511
    const float4* wp = (const float4*)(w2 + ((size_t)e*DIM + c) * HIDDEN);
    __shared__ float hs[TCD][HIDDEN];     // 32 KB
    for (int t0 = 0; t0 < n; t0 += TCD) {
        int tc = min(TCD, n - t0);
        __syncthreads();
        for (int i = tid; i < TCD*(HIDDEN/4); i += 256) {
            int j = i >> 8; int dd = i & 255;          // HIDDEN/4 = 256
            float4 v = make_float4(0.f, 0.f, 0.f, 0.f);
            if (j < tc) {
                int p = lists[e*TOKENS + t0 + j];
                v = *(const float4*)(act + (size_t)p*HIDDEN + dd*4);
            }
            *(float4*)&hs[j][dd*4] = v;
        }
        __syncthreads();
        float a[TCD];
        #pragma unroll
        for (int j = 0; j < TCD; ++j) a[j] = 0.f;
        #pragma unroll 4
        for (int i = 0; i < 16; ++i) {                 // 256 f4 / 16 splits
            int d4 = s + 16*i;
            float4 w = wp[d4];
            #pragma unroll
            for (int j = 0; j < TCD; ++j) {
                float4 hv = *(const float4*)&hs[j][d4*4];
                a[j] += w.x*hv.x + w.y*hv.y + w.z*hv.z + w.w*hv.w;
            }
        }
        #pragma unroll
        for (int j = 0; j < TCD; ++j) {
            #pragma unroll
            for (int m = 1; m < 16; m <<= 1) {
                a[j] += __shfl_xor(a[j], m);
            }
        }
        if (s == 0) {
            float bb = b2[e*DIM + c];
            for (int j = 0; j < tc; ++j) {
                int p = lists[e*TOKENS + t0 + j];
                h2[(size_t)p*DIM + c] = a[j] + bb;
            }
        }
    }
}

// ---------------- weighted combine ----------------
__global__ void combine_kernel(const float* __restrict__ h2, const float* __restrict__ eww,
                               float* __restrict__ out) {
    int i = blockIdx.x * 256 + threadIdx.x;   // 0..32767
    int b = i / DIM;
    int c = i % DIM;
    float s = 0.f;
    #pragma unroll
    for (int k = 0; k < TOPK; ++k) {
        s += eww[b*TOPK + k] * h2[(size_t)(b*TOPK + k)*DIM + c];
    }
    out[i] = s;
}

extern "C" void kernel_launch(void* const* d_in, const int* in_sizes, int n_in,
                              void* d_out, int out_size, void* d_ws, size_t ws_size,
                              hipStream_t stream) {
    const float* x  = (const float*)d_in[0];
    const float* Wg = (const float*)d_in[1];
    const float* bg = (const float*)d_in[2];
    const float* w1 = (const float*)d_in[3];
    const float* b1 = (const float*)d_in[4];
    const float* w2 = (const float*)d_in[5];
    const float* b2 = (const float*)d_in[6];
    float* out = (float*)d_out;

    char* ws = (char*)d_ws;
    int*   idxw   = (int*)(ws);                 // 256 ints
    float* eww    = (float*)(ws + 1024);        // 256 floats
    int*   counts = (int*)(ws + 2048);          // 32 ints
    int*   lists  = (int*)(ws + 4096);          // 32*64 ints
    float* act    = (float*)(ws + 16384);                          // 256*1024 f32 = 1 MB
    float* h2     = (float*)(ws + 16384 + (size_t)NPAIR*HIDDEN*4); // 256*512 f32 = 512 KB

    router_kernel<<<TOKENS, 64, 0, stream>>>(x, Wg, bg, idxw, eww);
    build_lists<<<1, 32, 0, stream>>>(idxw, counts, lists);
    expert_up<<<dim3(NEXP, HIDDEN/16), 256, 0, stream>>>(x, w1, b1, counts, lists, act);
    expert_down<<<dim3(NEXP, DIM/16), 256, 0, stream>>>(act, w2, b2, counts, lists, h2);
    combine_kernel<<<TOKENS*DIM/256, 256, 0, stream>>>(h2, eww, out);
}